// Round 9
// baseline (382.299 us; speedup 1.0000x reference)
//
#include <hip/hip_runtime.h>
#include <hip/hip_bf16.h>
#include <cstdint>

#define B_ROWS 4096
#define DIM 1024
#define NN 8192  // 2*B
#define GRID_BLOCKS 768

typedef int v4i __attribute__((ext_vector_type(4)));

__device__ __forceinline__ float wave_reduce_sum(float v) {
    v += __shfl_xor(v, 1);
    v += __shfl_xor(v, 2);
    v += __shfl_xor(v, 4);
    v += __shfl_xor(v, 8);
    v += __shfl_xor(v, 16);
    v += __shfl_xor(v, 32);
    return v;
}

__device__ __forceinline__ void gld_lds16(const void* g, void* l) {
    __builtin_amdgcn_global_load_lds(
        (__attribute__((address_space(1))) void*)(uintptr_t)g,
        (__attribute__((address_space(3))) void*)l, 16, 0, 0);
}

// Manual epoch grid barrier (R25). ctr zeroed per replay by hipMemsetAsync in
// kernel_launch (capture-legal; harness uses the same API). Epoch arithmetic:
// arrival k passes when ctr reaches the next multiple of GRID_BLOCKS above k.
// Safety: 49.2 KB LDS + __launch_bounds__(256,3) => exactly 3 blocks/CU x 256
// CU = 768 co-resident blocks, so every participant is running.
// Fencing: release-fence before arrive publishes rep/pos/denom stores;
// acquire-fence after the spin invalidates this CU's L1 (+XCD L2) so
// post-barrier reads see remote writes. Agent-scope atomic load in the spin
// reads coherently (bypasses stale cached lines).
__device__ __forceinline__ void grid_barrier(unsigned* ctr) {
    __syncthreads();
    if (threadIdx.x == 0) {
        __threadfence();  // release
        unsigned old = __hip_atomic_fetch_add(ctr, 1u, __ATOMIC_ACQ_REL,
                                              __HIP_MEMORY_SCOPE_AGENT);
        unsigned target = (old / GRID_BLOCKS + 1u) * GRID_BLOCKS;
        while (__hip_atomic_load(ctr, __ATOMIC_RELAXED,
                                 __HIP_MEMORY_SCOPE_AGENT) < target)
            __builtin_amdgcn_s_sleep(2);
        __threadfence();  // acquire
    }
    __syncthreads();
}

// R25: ONE fused kernel, PLAIN launch (R8's hipLaunchCooperativeKernel never
// executed under graph capture: absmax 9.0 == |0 - ref|, i.e. out stayed at
// memset-zero). Manual workspace barrier replaces cg::grid.sync().
//
// phase1 (norm+pos, zero denom/out) -> barrier -> phase2 (gemm over 2080
// tiles via dynamic atomic tile counter — no tail skew, no dispatch-order
// assumption) -> barrier -> phase3 (finish, blocks 0..31).
//
// Phase 2 = R0's measured-best gemm body (128x128 triangle tiles, 2x2 waves
// of 64x64, mfma_i32_16x16x64_i8, 0 bank conflicts, 3-buffer counted-vmcnt
// depth-2 pipeline — R1-R6 proved schedule/locality variations neutral)
// + R7's atomic-denom epilogue (passed, absmax 0.0). Per-tile end guard:
// lgkmcnt(0)+s_barrier before the next tile's prologue STAGE reuses LDS.
//
// K-perm trick (verified R0-R7): staging thread t -> row t>>2, global seg
// (t&3)^((sr>>1)&3), LDS slot t*16; fragment lane (cm,q) reads slot q^fsw,
// fsw=(cm>>1)&3. A-lane and B-lane hold the same 16 global-k bytes in the
// same order -> contraction invariant. rep is SIGNED i8 = round(127*x̂);
// |x̂| <= ~0.16 at D=1024 so no clamp; i32 MFMA accumulation exact.
__global__ __launch_bounds__(256, 3) void fused_kernel(
    const float* __restrict__ p1, const float* __restrict__ p2,
    signed char* __restrict__ rep, float* __restrict__ pos,
    float* __restrict__ denom, float* __restrict__ out,
    unsigned* __restrict__ ctrs) {
    __shared__ __align__(16) signed char As[3][8192];  // 24 KB
    __shared__ __align__(16) signed char Bs[3][8192];  // 24 KB
    __shared__ int s_ti;
    __shared__ float red[4];

    unsigned* bar_ctr = ctrs;       // barrier epoch counter
    unsigned* tile_ctr = ctrs + 4;  // dynamic tile counter (separate cacheline-ish)

    const int bid = blockIdx.x;
    const int t = threadIdx.x;
    const int lane = t & 63;
    const int wv = t >> 6;

    // ---------------- phase 1: normalize + positives (+ zero denom/out) ----
    if (bid < 32) denom[bid * 256 + t] = 0.f;
    if (bid == 0 && t == 0) out[0] = 0.f;

    for (int i = bid * 4 + wv; i < B_ROWS; i += 4 * GRID_BLOCKS) {
        const float4* ap = (const float4*)(p1 + (size_t)i * DIM);
        const float4* bp = (const float4*)(p2 + (size_t)i * DIM);
        float4 a[4], b[4];
#pragma unroll
        for (int c = 0; c < 4; ++c) { a[c] = ap[lane + 64 * c]; b[c] = bp[lane + 64 * c]; }
        float s1 = 0.f, s2 = 0.f, dp = 0.f;
#pragma unroll
        for (int c = 0; c < 4; ++c) {
            s1 += a[c].x * a[c].x + a[c].y * a[c].y + a[c].z * a[c].z + a[c].w * a[c].w;
            s2 += b[c].x * b[c].x + b[c].y * b[c].y + b[c].z * b[c].z + b[c].w * b[c].w;
            dp += a[c].x * b[c].x + a[c].y * b[c].y + a[c].z * b[c].z + a[c].w * b[c].w;
        }
        s1 = wave_reduce_sum(s1);
        s2 = wave_reduce_sum(s2);
        dp = wave_reduce_sum(dp);
        const float sc1 = rsqrtf(s1) * 127.0f, sc2 = rsqrtf(s2) * 127.0f;
        char4* o1 = (char4*)(rep + (size_t)i * DIM);
        char4* o2 = (char4*)(rep + (size_t)(i + B_ROWS) * DIM);
#pragma unroll
        for (int c = 0; c < 4; ++c) {
            char4 u1, u2;
            u1.x = (signed char)__float2int_rn(a[c].x * sc1);
            u1.y = (signed char)__float2int_rn(a[c].y * sc1);
            u1.z = (signed char)__float2int_rn(a[c].z * sc1);
            u1.w = (signed char)__float2int_rn(a[c].w * sc1);
            u2.x = (signed char)__float2int_rn(b[c].x * sc2);
            u2.y = (signed char)__float2int_rn(b[c].y * sc2);
            u2.z = (signed char)__float2int_rn(b[c].z * sc2);
            u2.w = (signed char)__float2int_rn(b[c].w * sc2);
            o1[lane + 64 * c] = u1;
            o2[lane + 64 * c] = u2;
        }
        if (lane == 0) pos[i] = dp * rsqrtf(s1) * rsqrtf(s2);
    }

    grid_barrier(bar_ctr);

    // ---------------- phase 2: fused symmetric GEMM, dynamic tiles ---------
    const int wr = wv >> 1;    // wave row-half
    const int wc = wv & 1;     // wave col-half
    const int cm = lane & 15;  // frag m,n index
    const int q = lane >> 4;   // frag k-quarter
    const int sr = t >> 2;
    const int sg = (t & 3) ^ ((sr >> 1) & 3);
    const int fsw = (cm >> 1) & 3;
    const int aOff = wr * 4096 + cm * 64 + ((q ^ fsw) << 4);
    const int bOff = wc * 4096 + cm * 64 + ((q ^ fsw) << 4);
    const float esc = 2.0f / 16129.0f;  // (1/T) / 127^2

    for (;;) {
        if (t == 0) s_ti = (int)atomicAdd(tile_ctr, 1u);
        __syncthreads();
        const int ti = s_ti;
        if (ti >= 2080) break;
        // rb-major triangle decode: start(rb) = 64*rb - rb*(rb-1)/2
        int rb = (int)(64.5f - sqrtf(4160.25f - 2.0f * (float)ti));
        while (64 * (rb + 1) - (rb + 1) * rb / 2 <= ti) ++rb;
        while (64 * rb - rb * (rb - 1) / 2 > ti) --rb;
        const int cb = rb + (ti - (64 * rb - rb * (rb - 1) / 2));

        const signed char* aS = rep + (size_t)(rb * 128 + sr) * DIM + sg * 16;
        const signed char* bS = rep + (size_t)(cb * 128 + sr) * DIM + sg * 16;

        v4i acc[4][4];
#pragma unroll
        for (int i = 0; i < 4; ++i)
#pragma unroll
            for (int j = 0; j < 4; ++j) acc[i][j] = (v4i){0, 0, 0, 0};

        auto STAGE = [&](signed char* Ad, signed char* Bd, int kk) {
            const signed char* a0 = aS + kk * 64;
            const signed char* b0 = bS + kk * 64;
            gld_lds16(a0, Ad + t * 16);                            // A rows 0..63
            gld_lds16(a0 + (size_t)64 * DIM, Ad + t * 16 + 4096);  // A rows 64..127
            gld_lds16(b0, Bd + t * 16);
            gld_lds16(b0 + (size_t)64 * DIM, Bd + t * 16 + 4096);
        };

        auto COMPUTE = [&](const signed char* Ab, const signed char* Bb) {
            v4i af[4], bf[4];
#pragma unroll
            for (int mi = 0; mi < 4; ++mi) af[mi] = *(const v4i*)(Ab + aOff + mi * 1024);
#pragma unroll
            for (int ni = 0; ni < 4; ++ni) bf[ni] = *(const v4i*)(Bb + bOff + ni * 1024);
#pragma unroll
            for (int mi = 0; mi < 4; ++mi)
#pragma unroll
                for (int ni = 0; ni < 4; ++ni)
                    acc[mi][ni] = __builtin_amdgcn_mfma_i32_16x16x64_i8(
                        af[mi], bf[ni], acc[mi][ni], 0, 0, 0);
        };

        // Prologue: stage tiles 0 and 1 (8 loads in flight).
        STAGE(As[0], Bs[0], 0);
        STAGE(As[1], Bs[1], 1);

#pragma unroll
        for (int kk = 0; kk < 14; ++kk) {
            asm volatile("s_waitcnt vmcnt(4)" ::: "memory");  // own tile done
            __builtin_amdgcn_s_barrier();
            STAGE(As[(kk + 2) % 3], Bs[(kk + 2) % 3], kk + 2);
            COMPUTE(As[kk % 3], Bs[kk % 3]);
        }
        asm volatile("s_waitcnt vmcnt(4)" ::: "memory");
        __builtin_amdgcn_s_barrier();
        COMPUTE(As[14 % 3], Bs[14 % 3]);
        asm volatile("s_waitcnt vmcnt(0)" ::: "memory");
        __builtin_amdgcn_s_barrier();
        COMPUTE(As[15 % 3], Bs[15 % 3]);

        // Epilogue: atomic accumulation into denom.
        // C/D: col = wc*64+ni*16+cm, row = wr*64+mi*16+q*4+reg.
        float colsum[4];
#pragma unroll
        for (int ni = 0; ni < 4; ++ni) colsum[ni] = 0.f;

#pragma unroll
        for (int mi = 0; mi < 4; ++mi) {
#pragma unroll
            for (int reg = 0; reg < 4; ++reg) {
                const int grow = rb * 128 + wr * 64 + mi * 16 + (q << 2) + reg;
                float rs = 0.f;
#pragma unroll
                for (int ni = 0; ni < 4; ++ni) {
                    const int gcol = cb * 128 + wc * 64 + ni * 16 + cm;
                    const float e =
                        (grow == gcol) ? 0.f : __expf((float)acc[mi][ni][reg] * esc);
                    rs += e;
                    colsum[ni] += e;
                }
                rs += __shfl_xor(rs, 1);
                rs += __shfl_xor(rs, 2);
                rs += __shfl_xor(rs, 4);
                rs += __shfl_xor(rs, 8);
                if (cm == 0) atomicAdd(denom + grow, rs);
            }
        }

        if (rb != cb) {
#pragma unroll
            for (int ni = 0; ni < 4; ++ni) {
                colsum[ni] += __shfl_xor(colsum[ni], 16);  // fold q
                colsum[ni] += __shfl_xor(colsum[ni], 32);
            }
            if (q == 0) {
#pragma unroll
                for (int ni = 0; ni < 4; ++ni)
                    atomicAdd(denom + cb * 128 + wc * 64 + ni * 16 + cm, colsum[ni]);
            }
        }

        // End-of-tile guard: all waves' ds_reads done before the next tile's
        // prologue STAGE (and s_ti rewrite) reuse LDS.
        asm volatile("s_waitcnt lgkmcnt(0)" ::: "memory");
        __builtin_amdgcn_s_barrier();
    }

    grid_barrier(bar_ctr);

    // ---------------- phase 3: finish (blocks 0..31) ----------------------
    if (bid < 32) {
        const int r = bid * 256 + t;  // 8192 rows
        float v = __logf(denom[r]) - pos[r & (B_ROWS - 1)] * 2.0f;
        v = wave_reduce_sum(v);
        if (lane == 0) red[wv] = v;
        __syncthreads();
        if (t == 0)
            atomicAdd(out, (red[0] + red[1] + red[2] + red[3]) * (1.0f / NN));
    }
}

extern "C" void kernel_launch(void* const* d_in, const int* in_sizes, int n_in,
                              void* d_out, int out_size, void* d_ws, size_t ws_size,
                              hipStream_t stream) {
    const float* p1 = (const float*)d_in[0];
    const float* p2 = (const float*)d_in[1];
    char* ws = (char*)d_ws;
    signed char* rep = (signed char*)ws;                            // 8 MiB (i8)
    float* pos = (float*)(ws + (size_t)8 * 1024 * 1024);            // 16 KiB
    float* denom = (float*)(ws + (size_t)8 * 1024 * 1024 + 16384);  // 32 KiB
    unsigned* ctrs = (unsigned*)(ws + (size_t)8 * 1024 * 1024 + 49152);  // 32 B
    float* out = (float*)d_out;

    hipMemsetAsync(ctrs, 0, 32, stream);  // zero barrier + tile counters
    fused_kernel<<<GRID_BLOCKS, 256, 0, stream>>>(p1, p2, rep, pos, denom, out,
                                                  ctrs);
}

// Round 10
// 175.986 us; speedup vs baseline: 2.1723x; 2.1723x over previous
//
#include <hip/hip_runtime.h>
#include <hip/hip_bf16.h>
#include <cstdint>

#define B_ROWS 4096
#define DIM 1024
#define NN 8192  // 2*B

typedef int v4i __attribute__((ext_vector_type(4)));

__device__ __forceinline__ float wave_reduce_sum(float v) {
    v += __shfl_xor(v, 1);
    v += __shfl_xor(v, 2);
    v += __shfl_xor(v, 4);
    v += __shfl_xor(v, 8);
    v += __shfl_xor(v, 16);
    v += __shfl_xor(v, 32);
    return v;
}

__device__ __forceinline__ void gld_lds16(const void* g, void* l) {
    __builtin_amdgcn_global_load_lds(
        (__attribute__((address_space(1))) void*)(uintptr_t)g,
        (__attribute__((address_space(3))) void*)l, 16, 0, 0);
}

// Kernel 1: L2-normalize + positives, ONE WAVE PER ROW-PAIR. No LDS/barriers.
// rep is SIGNED i8: round(127 * normalized). |x̂| <= ~0.16 for N(0,1) data at
// D=1024, so no clamp needed; i32 MFMA accumulation is exact.
// Also zeroes denom[8192] (blocks 0..31).
__global__ void norm_pos_kernel(const float* __restrict__ p1,
                                const float* __restrict__ p2,
                                signed char* __restrict__ rep,
                                float* __restrict__ pos,
                                float* __restrict__ denom) {
    if (blockIdx.x < 32) denom[blockIdx.x * 256 + threadIdx.x] = 0.f;
    const int wv = threadIdx.x >> 6, lane = threadIdx.x & 63;
    const int i = blockIdx.x * 4 + wv;  // 0..4095
    const float4* ap = (const float4*)(p1 + (size_t)i * DIM);
    const float4* bp = (const float4*)(p2 + (size_t)i * DIM);
    float4 a[4], b[4];
#pragma unroll
    for (int c = 0; c < 4; ++c) { a[c] = ap[lane + 64 * c]; b[c] = bp[lane + 64 * c]; }
    float s1 = 0.f, s2 = 0.f, dp = 0.f;
#pragma unroll
    for (int c = 0; c < 4; ++c) {
        s1 += a[c].x * a[c].x + a[c].y * a[c].y + a[c].z * a[c].z + a[c].w * a[c].w;
        s2 += b[c].x * b[c].x + b[c].y * b[c].y + b[c].z * b[c].z + b[c].w * b[c].w;
        dp += a[c].x * b[c].x + a[c].y * b[c].y + a[c].z * b[c].z + a[c].w * b[c].w;
    }
    s1 = wave_reduce_sum(s1);
    s2 = wave_reduce_sum(s2);
    dp = wave_reduce_sum(dp);
    const float sc1 = rsqrtf(s1) * 127.0f, sc2 = rsqrtf(s2) * 127.0f;
    char4* o1 = (char4*)(rep + (size_t)i * DIM);
    char4* o2 = (char4*)(rep + (size_t)(i + B_ROWS) * DIM);
#pragma unroll
    for (int c = 0; c < 4; ++c) {
        char4 u1, u2;
        u1.x = (signed char)__float2int_rn(a[c].x * sc1);
        u1.y = (signed char)__float2int_rn(a[c].y * sc1);
        u1.z = (signed char)__float2int_rn(a[c].z * sc1);
        u1.w = (signed char)__float2int_rn(a[c].w * sc1);
        u2.x = (signed char)__float2int_rn(b[c].x * sc2);
        u2.y = (signed char)__float2int_rn(b[c].y * sc2);
        u2.z = (signed char)__float2int_rn(b[c].z * sc2);
        u2.w = (signed char)__float2int_rn(b[c].w * sc2);
        o1[lane + 64 * c] = u1;
        o2[lane + 64 * c] = u2;
    }
    if (lane == 0) pos[i] = dp * rsqrtf(s1) * rsqrtf(s2);
}

// Kernel 2 (R26): R7's measured-best gemm (256x128 rect tiles, 4 waves of
// 64x128, 16x16x64 i8, m201-phased K-loop, atomic-denom epilogue, 57.3 us,
// absmax 0.0) + LAST-BLOCK FINISH (removes the 3rd kernel launch).
//
// Ledger: R0-R6 exonerated schedule (5 variants), tile/MFMA shape, occupancy,
// and L2 locality for the gemm plateau (~57 us, MFMA-busy constant 13.8 us =
// m233 structural regime). R8: cooperative launch no-ops under graph capture.
// R9: manual spin grid-barrier = +270 us stall (768 blocks agent-scope
// polling one line serializes at the coherence point) — single-kernel fusion
// is dead on this harness; kernel boundaries ARE the cheap barrier. The one
// remaining controllable cost: the finish launch — folded here via the
// last-block pattern (one fetch_add per block, NO spinning).
//
// Ordering: each block drains its denom atomics (vmcnt(0) + syncthreads +
// release fence) before incrementing done. The block that sees old==1055
// acquire-fences and reads denom with AGENT-scope atomic loads (bypasses
// stale local cache). pos was written by kernel 1 (kernel-boundary flush) —
// plain loads fine. out is memset to 0 by the harness each run; plain store.
// done is re-zeroed per replay by the hipMemsetAsync node (capture-legal,
// proven R9).
__global__ __launch_bounds__(256, 2) void gemm_kernel(const signed char* __restrict__ rep,
                                                      float* __restrict__ denom,
                                                      const float* __restrict__ pos,
                                                      float* __restrict__ out,
                                                      unsigned* __restrict__ done) {
    // XCD-chunked swizzle (1056 = 8*132, bijective)
    const int bid0 = blockIdx.x;
    const int bid = (bid0 & 7) * 132 + (bid0 >> 3);
    // decode: start(R) = R*(65-R), count 64-2R
    int rb = (int)((65.0f - sqrtf(4225.0f - 4.0f * (float)bid)) * 0.5f);
    while ((rb + 1) * (64 - rb) <= bid) ++rb;
    while (rb * (65 - rb) > bid) --rb;
    const int cb = 2 * rb + (bid - rb * (65 - rb));

    __shared__ __align__(16) signed char As[3][16384];  // 48 KB (256 rows x 64)
    __shared__ __align__(16) signed char Bs[3][8192];   // 24 KB (128 rows x 64)
    __shared__ float red[4];
    __shared__ unsigned s_rank;
    const int t = threadIdx.x;
    const int lane = t & 63;
    const int wv = t >> 6;     // 0..3: wave owns rows wv*64..wv*64+63 of the tile
    const int cm = lane & 15;  // frag m,n index
    const int q = lane >> 4;   // frag k-quarter

    // staging source
    const int sr = t >> 2;
    const int sg = (t & 3) ^ ((sr >> 1) & 3);
    const signed char* aS = rep + (size_t)(rb * 256 + sr) * DIM + sg * 16;
    const signed char* bS = rep + (size_t)(cb * 128 + sr) * DIM + sg * 16;

    // fragment read offsets (k-invariant): K-perm trick (verified R0-R7):
    // lane (cm,q) reads seg (q^fsw), fsw=(cm>>1)&3; A-lane and B-lane hold
    // the same 16 global-k bytes in the same order -> contraction invariant.
    const int fsw = (cm >> 1) & 3;
    const int aOff = wv * 4096 + cm * 64 + ((q ^ fsw) << 4);
    const int bOff = cm * 64 + ((q ^ fsw) << 4);

    v4i acc[4][8];
#pragma unroll
    for (int i = 0; i < 4; ++i)
#pragma unroll
        for (int j = 0; j < 8; ++j) acc[i][j] = (v4i){0, 0, 0, 0};

    // half-STAGE: part 0 = A rows 0..191; part 1 = A rows 192..255 + B.
    auto STAGE_HALF = [&](signed char* Ad, signed char* Bd, int kk, int part) {
        const signed char* a0 = aS + kk * 64;
        const signed char* b0 = bS + kk * 64;
        if (part == 0) {
            gld_lds16(a0, Ad + t * 16);                             // A rows 0..63
            gld_lds16(a0 + (size_t)64 * DIM, Ad + t * 16 + 4096);   // 64..127
            gld_lds16(a0 + (size_t)128 * DIM, Ad + t * 16 + 8192);  // 128..191
        } else {
            gld_lds16(a0 + (size_t)192 * DIM, Ad + t * 16 + 12288); // 192..255
            gld_lds16(b0, Bd + t * 16);                             // B rows 0..63
            gld_lds16(b0 + (size_t)64 * DIM, Bd + t * 16 + 4096);   // 64..127
        }
    };

    // Prologue: stage tiles 0 and 1; wait tile 0 (oldest 6) then barrier.
    STAGE_HALF(As[0], Bs[0], 0, 0);
    STAGE_HALF(As[0], Bs[0], 0, 1);
    STAGE_HALF(As[1], Bs[1], 1, 0);
    STAGE_HALF(As[1], Bs[1], 1, 1);
    asm volatile("s_waitcnt vmcnt(6)" ::: "memory");
    __builtin_amdgcn_s_barrier();

#pragma unroll
    for (int kk = 0; kk < 16; ++kk) {
        const signed char* Ab = As[kk % 3];
        const signed char* Bb = Bs[kk % 3];
        signed char* Ast = As[(kk + 2) % 3];
        signed char* Bst = Bs[(kk + 2) % 3];
        const bool do_stage = (kk < 14);

        // ---- phase A: read af0-3 + bf0-3, stage half, MFMA ni 0-3 ----
        v4i af[4], bf[4];
#pragma unroll
        for (int mi = 0; mi < 4; ++mi) af[mi] = *(const v4i*)(Ab + aOff + mi * 1024);
#pragma unroll
        for (int ni = 0; ni < 4; ++ni) bf[ni] = *(const v4i*)(Bb + bOff + ni * 1024);
        if (do_stage) STAGE_HALF(Ast, Bst, kk + 2, 0);
        __builtin_amdgcn_sched_barrier(0);
        __builtin_amdgcn_s_barrier();
        asm volatile("s_waitcnt lgkmcnt(0)" ::: "memory");
        __builtin_amdgcn_sched_barrier(0);
        __builtin_amdgcn_s_setprio(1);
#pragma unroll
        for (int mi = 0; mi < 4; ++mi)
#pragma unroll
            for (int ni = 0; ni < 4; ++ni)
                acc[mi][ni] = __builtin_amdgcn_mfma_i32_16x16x64_i8(
                    af[mi], bf[ni], acc[mi][ni], 0, 0, 0);
        __builtin_amdgcn_s_setprio(0);
        __builtin_amdgcn_sched_barrier(0);
        __builtin_amdgcn_s_barrier();

        // ---- phase B: read bf4-7, stage other half, MFMA ni 4-7 ----
#pragma unroll
        for (int ni = 0; ni < 4; ++ni)
            bf[ni] = *(const v4i*)(Bb + bOff + 4096 + ni * 1024);
        if (do_stage) STAGE_HALF(Ast, Bst, kk + 2, 1);
        __builtin_amdgcn_sched_barrier(0);
        __builtin_amdgcn_s_barrier();
        asm volatile("s_waitcnt lgkmcnt(0)" ::: "memory");
        __builtin_amdgcn_sched_barrier(0);
        __builtin_amdgcn_s_setprio(1);
#pragma unroll
        for (int mi = 0; mi < 4; ++mi)
#pragma unroll
            for (int ni = 0; ni < 4; ++ni)
                acc[mi][4 + ni] = __builtin_amdgcn_mfma_i32_16x16x64_i8(
                    af[mi], bf[ni], acc[mi][4 + ni], 0, 0, 0);
        __builtin_amdgcn_s_setprio(0);
        __builtin_amdgcn_sched_barrier(0);

        // ---- tile end: counted wait for next buffer, then block-wide sync.
        if (kk < 14) {
            asm volatile("s_waitcnt vmcnt(6)" ::: "memory");  // tile kk+1 resident
            __builtin_amdgcn_s_barrier();
        } else if (kk == 14) {
            asm volatile("s_waitcnt vmcnt(0)" ::: "memory");  // tile 15 resident
            __builtin_amdgcn_s_barrier();
        }
    }

    // Epilogue: atomic accumulation into denom[8192].
    // C/D: col = ni*16 + cm (tile-local), row = wv*64 + mi*16 + q*4 + reg.
    const float esc = 2.0f / 16129.0f;  // (1/T) / 127^2
    float colsum[8];
#pragma unroll
    for (int ni = 0; ni < 8; ++ni) colsum[ni] = 0.f;

#pragma unroll
    for (int mi = 0; mi < 4; ++mi) {
#pragma unroll
        for (int reg = 0; reg < 4; ++reg) {
            const int grow = rb * 256 + wv * 64 + mi * 16 + (q << 2) + reg;
            float rs = 0.f;
#pragma unroll
            for (int ni = 0; ni < 8; ++ni) {
                const int gcol = cb * 128 + ni * 16 + cm;
                const float e =
                    (grow == gcol) ? 0.f : __expf((float)acc[mi][ni][reg] * esc);
                rs += e;
                colsum[ni] += e;
            }
            rs += __shfl_xor(rs, 1);
            rs += __shfl_xor(rs, 2);
            rs += __shfl_xor(rs, 4);
            rs += __shfl_xor(rs, 8);
            if (cm == 0) atomicAdd(denom + grow, rs);  // rowsum
        }
    }

    // colsum: include only pairs whose primary tile is NOT in the set.
    const bool pred = (2 * rb + (wv >> 1)) < 2 * (cb >> 1);
#pragma unroll
    for (int ni = 0; ni < 8; ++ni) {
        colsum[ni] += __shfl_xor(colsum[ni], 16);  // fold q (rows)
        colsum[ni] += __shfl_xor(colsum[ni], 32);
    }
    if (pred && q == 0) {
#pragma unroll
        for (int ni = 0; ni < 8; ++ni)
            atomicAdd(denom + cb * 128 + ni * 16 + cm, colsum[ni]);
    }

    // ---- last-block finish (replaces the 3rd kernel) ----
    asm volatile("s_waitcnt vmcnt(0)" ::: "memory");  // this block's atomics drained
    __syncthreads();
    if (t == 0) {
        __threadfence();  // release: order our atomics before the increment
        s_rank = __hip_atomic_fetch_add(done, 1u, __ATOMIC_ACQ_REL,
                                        __HIP_MEMORY_SCOPE_AGENT);
    }
    __syncthreads();
    if (s_rank == 1055u) {  // all 1056 blocks' denom contributions visible
        __threadfence();    // acquire
        float a = 0.f;
        for (int r = t; r < NN; r += 256) {
            const float d = __hip_atomic_load(denom + r, __ATOMIC_RELAXED,
                                              __HIP_MEMORY_SCOPE_AGENT);
            a += __logf(d) - pos[r & (B_ROWS - 1)] * 2.0f;
        }
        a = wave_reduce_sum(a);
        if (lane == 0) red[wv] = a;
        __syncthreads();
        if (t == 0) out[0] = (red[0] + red[1] + red[2] + red[3]) * (1.0f / NN);
    }
}

extern "C" void kernel_launch(void* const* d_in, const int* in_sizes, int n_in,
                              void* d_out, int out_size, void* d_ws, size_t ws_size,
                              hipStream_t stream) {
    const float* p1 = (const float*)d_in[0];
    const float* p2 = (const float*)d_in[1];
    char* ws = (char*)d_ws;
    signed char* rep = (signed char*)ws;                            // 8 MiB (i8)
    float* pos = (float*)(ws + (size_t)8 * 1024 * 1024);            // 16 KiB
    float* denom = (float*)(ws + (size_t)8 * 1024 * 1024 + 16384);  // 32 KiB
    unsigned* done = (unsigned*)(ws + (size_t)8 * 1024 * 1024 + 49152);  // 32 B
    float* out = (float*)d_out;

    hipMemsetAsync(done, 0, 32, stream);  // re-zero per replay (capture-legal)
    norm_pos_kernel<<<1024, 256, 0, stream>>>(p1, p2, rep, pos, denom);
    gemm_kernel<<<1056, 256, 0, stream>>>(rep, denom, pos, out, done);
}

// Round 11
// 134.848 us; speedup vs baseline: 2.8350x; 1.3051x over previous
//
#include <hip/hip_runtime.h>
#include <hip/hip_bf16.h>
#include <cstdint>

#define B_ROWS 4096
#define DIM 1024
#define NN 8192  // 2*B

typedef int v4i __attribute__((ext_vector_type(4)));

__device__ __forceinline__ float wave_reduce_sum(float v) {
    v += __shfl_xor(v, 1);
    v += __shfl_xor(v, 2);
    v += __shfl_xor(v, 4);
    v += __shfl_xor(v, 8);
    v += __shfl_xor(v, 16);
    v += __shfl_xor(v, 32);
    return v;
}

__device__ __forceinline__ void gld_lds16(const void* g, void* l) {
    __builtin_amdgcn_global_load_lds(
        (__attribute__((address_space(1))) void*)(uintptr_t)g,
        (__attribute__((address_space(3))) void*)l, 16, 0, 0);
}

// Kernel 1: L2-normalize + positives, ONE WAVE PER ROW-PAIR. No LDS/barriers.
// rep is SIGNED i8: round(127 * normalized). |x̂| <= ~0.16 for N(0,1) data at
// D=1024, so no clamp needed; i32 MFMA accumulation is exact.
// Also zeroes denom[8192] and out[0].
__global__ void norm_pos_kernel(const float* __restrict__ p1,
                                const float* __restrict__ p2,
                                signed char* __restrict__ rep,
                                float* __restrict__ pos,
                                float* __restrict__ denom,
                                float* __restrict__ out) {
    if (blockIdx.x < 32) denom[blockIdx.x * 256 + threadIdx.x] = 0.f;
    if (blockIdx.x == 0 && threadIdx.x == 0) out[0] = 0.f;
    const int wv = threadIdx.x >> 6, lane = threadIdx.x & 63;
    const int i = blockIdx.x * 4 + wv;  // 0..4095
    const float4* ap = (const float4*)(p1 + (size_t)i * DIM);
    const float4* bp = (const float4*)(p2 + (size_t)i * DIM);
    float4 a[4], b[4];
#pragma unroll
    for (int c = 0; c < 4; ++c) { a[c] = ap[lane + 64 * c]; b[c] = bp[lane + 64 * c]; }
    float s1 = 0.f, s2 = 0.f, dp = 0.f;
#pragma unroll
    for (int c = 0; c < 4; ++c) {
        s1 += a[c].x * a[c].x + a[c].y * a[c].y + a[c].z * a[c].z + a[c].w * a[c].w;
        s2 += b[c].x * b[c].x + b[c].y * b[c].y + b[c].z * b[c].z + b[c].w * b[c].w;
        dp += a[c].x * b[c].x + a[c].y * b[c].y + a[c].z * b[c].z + a[c].w * b[c].w;
    }
    s1 = wave_reduce_sum(s1);
    s2 = wave_reduce_sum(s2);
    dp = wave_reduce_sum(dp);
    const float sc1 = rsqrtf(s1) * 127.0f, sc2 = rsqrtf(s2) * 127.0f;
    char4* o1 = (char4*)(rep + (size_t)i * DIM);
    char4* o2 = (char4*)(rep + (size_t)(i + B_ROWS) * DIM);
#pragma unroll
    for (int c = 0; c < 4; ++c) {
        char4 u1, u2;
        u1.x = (signed char)__float2int_rn(a[c].x * sc1);
        u1.y = (signed char)__float2int_rn(a[c].y * sc1);
        u1.z = (signed char)__float2int_rn(a[c].z * sc1);
        u1.w = (signed char)__float2int_rn(a[c].w * sc1);
        u2.x = (signed char)__float2int_rn(b[c].x * sc2);
        u2.y = (signed char)__float2int_rn(b[c].y * sc2);
        u2.z = (signed char)__float2int_rn(b[c].z * sc2);
        u2.w = (signed char)__float2int_rn(b[c].w * sc2);
        o1[lane + 64 * c] = u1;
        o2[lane + 64 * c] = u2;
    }
    if (lane == 0) pos[i] = dp * rsqrtf(s1) * rsqrtf(s2);
}

// Kernel 2 (R27): 256x128 tiles, *** 512 THREADS / 8 WAVES *** (the untested
// catalog quadrant: m230b 8ph works with 8-wave role-split; m232 4-wave 8ph
// failed to reproduce overlap — all our phased attempts were 4-wave).
// Wave grid 4(wr) x 2(wc), wave tile 64x64 -> acc 16 v4i = 64 VGPR ->
// 2 blocks/CU at __launch_bounds__(512,4), 16 waves/CU. LDS 3 x (A 16KB +
// B 8KB) = 72 KB, depth-2 prefetch, counted vmcnt(3) once per K-tile.
// Per K-tile 2 fine phases: {6 ds_read | 2 gld A -> sbar -> barrier ->
// lgkm0 -> setprio1 -> 8 MFMA -> setprio0 -> barrier} then {2 ds_read |
// 1 gld B -> ... -> 8 MFMA}.
//
// Ledger: R0-R6 exonerated schedule(5)/shape(2)/MFMA-shape(2)/occupancy(2)/
// L2-locality for the 4-wave plateau (56-70 us, MFMA-busy const 13.8 us).
// R8: coop launch no-ops under capture. R9/R10: in-kernel device-scope sync
// (spin barrier, last-block fence) costs +47..+270 us — kernel boundaries
// ARE the cheap barrier. Harness-fixed floor ~54-65 us (R9: 1-kernel total
// minus kernel dur = 54 us). This round: the 8-wave structural gate.
//
// Tiling (R4/R7, verified): tiles (R,C) rows [256R,..+256) cols [128C,..+128),
// set {C>=2R}, 1056 tiles, start(R)=R*(65-R). Pair (i,j) counted by ROWSUM
// of its primary tile when in set; else by COLSUM of the mirror tile,
// predicated per-wave: half=wr>>1, pred = (2rb+half) < 2(cb>>1). Diagonal
// masked in-place. Atomic-denom epilogue (R7, passed absmax 0.0).
// K-perm trick: staging thread t -> row t>>2, global seg (t&3)^((sr>>1)&3),
// LDS slot t*16; frag lane (cm,q) reads slot q^fsw, fsw=(cm>>1)&3 -> A and
// B lanes hold the same 16 global-k bytes in the same order.
__global__ __launch_bounds__(512, 4) void gemm_kernel(const signed char* __restrict__ rep,
                                                      float* __restrict__ denom) {
    // XCD-chunked swizzle (1056 = 8*132, bijective)
    const int bid0 = blockIdx.x;
    const int bid = (bid0 & 7) * 132 + (bid0 >> 3);
    // decode: start(R) = R*(65-R), count 64-2R
    int rb = (int)((65.0f - sqrtf(4225.0f - 4.0f * (float)bid)) * 0.5f);
    while ((rb + 1) * (64 - rb) <= bid) ++rb;
    while (rb * (65 - rb) > bid) --rb;
    const int cb = 2 * rb + (bid - rb * (65 - rb));

    __shared__ __align__(16) signed char As[3][16384];  // 48 KB (256 rows x 64)
    __shared__ __align__(16) signed char Bs[3][8192];   // 24 KB (128 rows x 64)
    const int t = threadIdx.x;
    const int lane = t & 63;
    const int wv = t >> 6;     // 0..7
    const int wr = wv >> 1;    // 0..3: 64-row strip
    const int wc = wv & 1;     // 0..1: 64-col strip
    const int cm = lane & 15;  // frag m,n index
    const int q = lane >> 4;   // frag k-quarter

    // staging source: 512 threads x 16B = 8 KB = 128 rows per gld call.
    const int sr = t >> 2;  // 0..127
    const int sg = (t & 3) ^ ((sr >> 1) & 3);
    const signed char* aS = rep + (size_t)(rb * 256 + sr) * DIM + sg * 16;
    const signed char* bS = rep + (size_t)(cb * 128 + sr) * DIM + sg * 16;

    // fragment read offsets (k-invariant)
    const int fsw = (cm >> 1) & 3;
    const int aOff = (wr * 64 + cm) * 64 + ((q ^ fsw) << 4);
    const int bOff = (wc * 64 + cm) * 64 + ((q ^ fsw) << 4);

    v4i acc[4][4];
#pragma unroll
    for (int i = 0; i < 4; ++i)
#pragma unroll
        for (int j = 0; j < 4; ++j) acc[i][j] = (v4i){0, 0, 0, 0};

    // stage parts: 0 = A rows 0..127; 1 = A rows 128..255; 2 = B (128 rows).
    auto STAGE_PART = [&](signed char* Ad, signed char* Bd, int kk, int part) {
        if (part == 0) {
            gld_lds16(aS + kk * 64, Ad + t * 16);
        } else if (part == 1) {
            gld_lds16(aS + kk * 64 + (size_t)128 * DIM, Ad + t * 16 + 8192);
        } else {
            gld_lds16(bS + kk * 64, Bd + t * 16);
        }
    };

    // Prologue: stage tiles 0 and 1 (6 loads); wait tile 0 (oldest 3).
    STAGE_PART(As[0], Bs[0], 0, 0);
    STAGE_PART(As[0], Bs[0], 0, 1);
    STAGE_PART(As[0], Bs[0], 0, 2);
    STAGE_PART(As[1], Bs[1], 1, 0);
    STAGE_PART(As[1], Bs[1], 1, 1);
    STAGE_PART(As[1], Bs[1], 1, 2);
    asm volatile("s_waitcnt vmcnt(3)" ::: "memory");
    __builtin_amdgcn_s_barrier();

#pragma unroll
    for (int kk = 0; kk < 16; ++kk) {
        const signed char* Ab = As[kk % 3];
        const signed char* Bb = Bs[kk % 3];
        signed char* Ast = As[(kk + 2) % 3];
        signed char* Bst = Bs[(kk + 2) % 3];
        const bool do_stage = (kk < 14);

        // ---- phase A: read af0-3 + bf0-1, stage A halves, MFMA ni 0-1 ----
        v4i af[4], bf[2];
#pragma unroll
        for (int mi = 0; mi < 4; ++mi) af[mi] = *(const v4i*)(Ab + aOff + mi * 1024);
#pragma unroll
        for (int ni = 0; ni < 2; ++ni) bf[ni] = *(const v4i*)(Bb + bOff + ni * 1024);
        if (do_stage) {
            STAGE_PART(Ast, Bst, kk + 2, 0);
            STAGE_PART(Ast, Bst, kk + 2, 1);
        }
        __builtin_amdgcn_sched_barrier(0);
        __builtin_amdgcn_s_barrier();
        asm volatile("s_waitcnt lgkmcnt(0)" ::: "memory");
        __builtin_amdgcn_sched_barrier(0);
        __builtin_amdgcn_s_setprio(1);
#pragma unroll
        for (int mi = 0; mi < 4; ++mi)
#pragma unroll
            for (int ni = 0; ni < 2; ++ni)
                acc[mi][ni] = __builtin_amdgcn_mfma_i32_16x16x64_i8(
                    af[mi], bf[ni], acc[mi][ni], 0, 0, 0);
        __builtin_amdgcn_s_setprio(0);
        __builtin_amdgcn_sched_barrier(0);
        __builtin_amdgcn_s_barrier();

        // ---- phase B: read bf2-3, stage B, MFMA ni 2-3 ----
#pragma unroll
        for (int ni = 0; ni < 2; ++ni)
            bf[ni] = *(const v4i*)(Bb + bOff + (2 + ni) * 1024);
        if (do_stage) STAGE_PART(Ast, Bst, kk + 2, 2);
        __builtin_amdgcn_sched_barrier(0);
        __builtin_amdgcn_s_barrier();
        asm volatile("s_waitcnt lgkmcnt(0)" ::: "memory");
        __builtin_amdgcn_sched_barrier(0);
        __builtin_amdgcn_s_setprio(1);
#pragma unroll
        for (int mi = 0; mi < 4; ++mi)
#pragma unroll
            for (int ni = 0; ni < 2; ++ni)
                acc[mi][2 + ni] = __builtin_amdgcn_mfma_i32_16x16x64_i8(
                    af[mi], bf[ni], acc[mi][2 + ni], 0, 0, 0);
        __builtin_amdgcn_s_setprio(0);
        __builtin_amdgcn_sched_barrier(0);

        // ---- tile end: counted wait for next buffer, then block-wide sync.
        if (kk < 14) {
            asm volatile("s_waitcnt vmcnt(3)" ::: "memory");  // tile kk+1 resident
            __builtin_amdgcn_s_barrier();
        } else if (kk == 14) {
            asm volatile("s_waitcnt vmcnt(0)" ::: "memory");  // tile 15 resident
            __builtin_amdgcn_s_barrier();
        }
    }

    // Epilogue: atomic accumulation into denom[8192] (R7, verified).
    // C/D: col = cb*128 + wc*64 + ni*16 + cm; row = rb*256 + wr*64 + mi*16
    // + q*4 + reg. Both wc waves atomicAdd their 64-col partial per row.
    const float esc = 2.0f / 16129.0f;  // (1/T) / 127^2
    float colsum[4];
#pragma unroll
    for (int ni = 0; ni < 4; ++ni) colsum[ni] = 0.f;

#pragma unroll
    for (int mi = 0; mi < 4; ++mi) {
#pragma unroll
        for (int reg = 0; reg < 4; ++reg) {
            const int grow = rb * 256 + wr * 64 + mi * 16 + (q << 2) + reg;
            float rs = 0.f;
#pragma unroll
            for (int ni = 0; ni < 4; ++ni) {
                const int gcol = cb * 128 + wc * 64 + ni * 16 + cm;
                const float e =
                    (grow == gcol) ? 0.f : __expf((float)acc[mi][ni][reg] * esc);
                rs += e;
                colsum[ni] += e;
            }
            rs += __shfl_xor(rs, 1);
            rs += __shfl_xor(rs, 2);
            rs += __shfl_xor(rs, 4);
            rs += __shfl_xor(rs, 8);
            if (cm == 0) atomicAdd(denom + grow, rs);  // rowsum partial
        }
    }

    // colsum: include only pairs whose primary tile is NOT in the set.
    // 128-row half of this wave: wr>>1.
    const bool pred = (2 * rb + (wr >> 1)) < 2 * (cb >> 1);
#pragma unroll
    for (int ni = 0; ni < 4; ++ni) {
        colsum[ni] += __shfl_xor(colsum[ni], 16);  // fold q (rows)
        colsum[ni] += __shfl_xor(colsum[ni], 32);
    }
    if (pred && q == 0) {
#pragma unroll
        for (int ni = 0; ni < 4; ++ni)
            atomicAdd(denom + cb * 128 + wc * 64 + ni * 16 + cm, colsum[ni]);
    }
}

// Kernel 3: finish — one thread per row: loss_r = log(denom_r) - 2*pos,
// block-reduce, single atomicAdd per block into out (out zeroed by kernel 1).
__global__ void finish_kernel(const float* __restrict__ denom,
                              const float* __restrict__ pos,
                              float* __restrict__ out) {
    const int r = blockIdx.x * 256 + threadIdx.x;  // 32 x 256 = 8192
    float v = __logf(denom[r]) - pos[r & (B_ROWS - 1)] * 2.0f;
    v = wave_reduce_sum(v);
    __shared__ float red[4];
    const int lane = threadIdx.x & 63, wv = threadIdx.x >> 6;
    if (lane == 0) red[wv] = v;
    __syncthreads();
    if (threadIdx.x == 0)
        atomicAdd(out, (red[0] + red[1] + red[2] + red[3]) * (1.0f / NN));
}

extern "C" void kernel_launch(void* const* d_in, const int* in_sizes, int n_in,
                              void* d_out, int out_size, void* d_ws, size_t ws_size,
                              hipStream_t stream) {
    const float* p1 = (const float*)d_in[0];
    const float* p2 = (const float*)d_in[1];
    char* ws = (char*)d_ws;
    signed char* rep = (signed char*)ws;                            // 8 MiB (i8)
    float* pos = (float*)(ws + (size_t)8 * 1024 * 1024);            // 16 KiB
    float* denom = (float*)(ws + (size_t)8 * 1024 * 1024 + 16384);  // 32 KiB
    float* out = (float*)d_out;

    norm_pos_kernel<<<1024, 256, 0, stream>>>(p1, p2, rep, pos, denom, out);
    gemm_kernel<<<1056, 512, 0, stream>>>(rep, denom);
    finish_kernel<<<32, 256, 0, stream>>>(denom, pos, out);
}

// Round 12
// 128.651 us; speedup vs baseline: 2.9716x; 1.0482x over previous
//
#include <hip/hip_runtime.h>
#include <hip/hip_bf16.h>
#include <cstdint>

#define B_ROWS 4096
#define DIM 1024
#define NN 8192  // 2*B

typedef int v4i __attribute__((ext_vector_type(4)));

__device__ __forceinline__ float wave_reduce_sum(float v) {
    v += __shfl_xor(v, 1);
    v += __shfl_xor(v, 2);
    v += __shfl_xor(v, 4);
    v += __shfl_xor(v, 8);
    v += __shfl_xor(v, 16);
    v += __shfl_xor(v, 32);
    return v;
}

__device__ __forceinline__ void gld_lds16(const void* g, void* l) {
    __builtin_amdgcn_global_load_lds(
        (__attribute__((address_space(1))) void*)(uintptr_t)g,
        (__attribute__((address_space(3))) void*)l, 16, 0, 0);
}

// FINAL (R28 = R7 revert, the measured-best configuration: 129.4 us).
//
// Session ledger (11 rounds):
//  - gemm plateau 56-70 us across: 6 schedules (drain-barrier, 2-phase dbuf,
//    counted-vmcnt depth-2, m201 fine-phased 4-wave, band-walk, 8-wave
//    fine-phased), 2 tile shapes, 2 MFMA shapes, 3 occupancies, L2-resident
//    walk (FETCH 63->20 MB, time flat). MFMA-pipe-busy constant ~13.8 us in
//    EVERY variant = m233 structural regime; per-MFMA cost 3.1x ubench,
//    invariant to everything tried.
//  - R8: hipLaunchCooperativeKernel silently no-ops under graph capture.
//  - R9: manual spin grid-barrier +270 us (agent-scope polling serializes at
//    the cross-XCD coherence point). R10: last-block fence +47 us. On this
//    machine KERNEL BOUNDARIES are the only cheap grid barrier.
//  - Harness-fixed residual ~55-65 us independent of kernel count (R9:
//    single-kernel total minus kernel dur = 54 us).
//  Composed floor: gemm 57 + norm ~9 + finish ~2 + residual ~58 ~= 127 us.
//  This variant measured 129.4 us -> within ~2% of the floor.
//
// Kernel 1: L2-normalize + positives, one wave per row-pair; rep = SIGNED i8
// round(127*x̂) (|x̂|<=~0.16 at D=1024 -> no clamp; i32 MFMA exact).
// Also zeroes denom and out.
__global__ void norm_pos_kernel(const float* __restrict__ p1,
                                const float* __restrict__ p2,
                                signed char* __restrict__ rep,
                                float* __restrict__ pos,
                                float* __restrict__ denom,
                                float* __restrict__ out) {
    if (blockIdx.x < 32) denom[blockIdx.x * 256 + threadIdx.x] = 0.f;
    if (blockIdx.x == 0 && threadIdx.x == 0) out[0] = 0.f;
    const int wv = threadIdx.x >> 6, lane = threadIdx.x & 63;
    const int i = blockIdx.x * 4 + wv;  // 0..4095
    const float4* ap = (const float4*)(p1 + (size_t)i * DIM);
    const float4* bp = (const float4*)(p2 + (size_t)i * DIM);
    float4 a[4], b[4];
#pragma unroll
    for (int c = 0; c < 4; ++c) { a[c] = ap[lane + 64 * c]; b[c] = bp[lane + 64 * c]; }
    float s1 = 0.f, s2 = 0.f, dp = 0.f;
#pragma unroll
    for (int c = 0; c < 4; ++c) {
        s1 += a[c].x * a[c].x + a[c].y * a[c].y + a[c].z * a[c].z + a[c].w * a[c].w;
        s2 += b[c].x * b[c].x + b[c].y * b[c].y + b[c].z * b[c].z + b[c].w * b[c].w;
        dp += a[c].x * b[c].x + a[c].y * b[c].y + a[c].z * b[c].z + a[c].w * b[c].w;
    }
    s1 = wave_reduce_sum(s1);
    s2 = wave_reduce_sum(s2);
    dp = wave_reduce_sum(dp);
    const float sc1 = rsqrtf(s1) * 127.0f, sc2 = rsqrtf(s2) * 127.0f;
    char4* o1 = (char4*)(rep + (size_t)i * DIM);
    char4* o2 = (char4*)(rep + (size_t)(i + B_ROWS) * DIM);
#pragma unroll
    for (int c = 0; c < 4; ++c) {
        char4 u1, u2;
        u1.x = (signed char)__float2int_rn(a[c].x * sc1);
        u1.y = (signed char)__float2int_rn(a[c].y * sc1);
        u1.z = (signed char)__float2int_rn(a[c].z * sc1);
        u1.w = (signed char)__float2int_rn(a[c].w * sc1);
        u2.x = (signed char)__float2int_rn(b[c].x * sc2);
        u2.y = (signed char)__float2int_rn(b[c].y * sc2);
        u2.z = (signed char)__float2int_rn(b[c].z * sc2);
        u2.w = (signed char)__float2int_rn(b[c].w * sc2);
        o1[lane + 64 * c] = u1;
        o2[lane + 64 * c] = u2;
    }
    if (lane == 0) pos[i] = dp * rsqrtf(s1) * rsqrtf(s2);
}

// Kernel 2: 256x128 rect tiles, 4 waves of 64x128, mfma_i32_16x16x64_i8,
// m201-phased K-loop, atomic-denom epilogue. Measured 57.3 us, absmax 0.0.
//
// Tiling: tiles (R,C): rows [256R,..+256), cols [128C,..+128), set {C>=2R};
// 1056 tiles, start(R)=R*(65-R). Pair (i,j) counted by ROWSUM of its primary
// tile when in set; else by COLSUM of the mirror tile, predicated per-wave
// (2rb+(wv>>1) < 2(cb>>1), wave-uniform). Diagonal masked in-place.
// K-perm trick: staging thread t -> row t>>2, global seg (t&3)^((sr>>1)&3),
// LDS slot t*16; frag lane (cm,q) reads slot q^fsw, fsw=(cm>>1)&3 -> A-lane
// and B-lane hold the same 16 global-k bytes in the same order ->
// contraction invariant.
__global__ __launch_bounds__(256, 2) void gemm_kernel(const signed char* __restrict__ rep,
                                                      float* __restrict__ denom) {
    // XCD-chunked swizzle (1056 = 8*132, bijective)
    const int bid0 = blockIdx.x;
    const int bid = (bid0 & 7) * 132 + (bid0 >> 3);
    // decode: start(R) = R*(65-R), count 64-2R
    int rb = (int)((65.0f - sqrtf(4225.0f - 4.0f * (float)bid)) * 0.5f);
    while ((rb + 1) * (64 - rb) <= bid) ++rb;
    while (rb * (65 - rb) > bid) --rb;
    const int cb = 2 * rb + (bid - rb * (65 - rb));

    __shared__ __align__(16) signed char As[3][16384];  // 48 KB (256 rows x 64)
    __shared__ __align__(16) signed char Bs[3][8192];   // 24 KB (128 rows x 64)
    const int t = threadIdx.x;
    const int lane = t & 63;
    const int wv = t >> 6;     // 0..3: wave owns rows wv*64..wv*64+63 of the tile
    const int cm = lane & 15;  // frag m,n index
    const int q = lane >> 4;   // frag k-quarter

    // staging source
    const int sr = t >> 2;
    const int sg = (t & 3) ^ ((sr >> 1) & 3);
    const signed char* aS = rep + (size_t)(rb * 256 + sr) * DIM + sg * 16;
    const signed char* bS = rep + (size_t)(cb * 128 + sr) * DIM + sg * 16;

    // fragment read offsets (k-invariant)
    const int fsw = (cm >> 1) & 3;
    const int aOff = wv * 4096 + cm * 64 + ((q ^ fsw) << 4);
    const int bOff = cm * 64 + ((q ^ fsw) << 4);

    v4i acc[4][8];
#pragma unroll
    for (int i = 0; i < 4; ++i)
#pragma unroll
        for (int j = 0; j < 8; ++j) acc[i][j] = (v4i){0, 0, 0, 0};

    // half-STAGE: part 0 = A rows 0..191; part 1 = A rows 192..255 + B.
    auto STAGE_HALF = [&](signed char* Ad, signed char* Bd, int kk, int part) {
        const signed char* a0 = aS + kk * 64;
        const signed char* b0 = bS + kk * 64;
        if (part == 0) {
            gld_lds16(a0, Ad + t * 16);                             // A rows 0..63
            gld_lds16(a0 + (size_t)64 * DIM, Ad + t * 16 + 4096);   // 64..127
            gld_lds16(a0 + (size_t)128 * DIM, Ad + t * 16 + 8192);  // 128..191
        } else {
            gld_lds16(a0 + (size_t)192 * DIM, Ad + t * 16 + 12288); // 192..255
            gld_lds16(b0, Bd + t * 16);                             // B rows 0..63
            gld_lds16(b0 + (size_t)64 * DIM, Bd + t * 16 + 4096);   // 64..127
        }
    };

    // Prologue: stage tiles 0 and 1; wait tile 0 (oldest 6) then barrier.
    STAGE_HALF(As[0], Bs[0], 0, 0);
    STAGE_HALF(As[0], Bs[0], 0, 1);
    STAGE_HALF(As[1], Bs[1], 1, 0);
    STAGE_HALF(As[1], Bs[1], 1, 1);
    asm volatile("s_waitcnt vmcnt(6)" ::: "memory");
    __builtin_amdgcn_s_barrier();

#pragma unroll
    for (int kk = 0; kk < 16; ++kk) {
        const signed char* Ab = As[kk % 3];
        const signed char* Bb = Bs[kk % 3];
        signed char* Ast = As[(kk + 2) % 3];
        signed char* Bst = Bs[(kk + 2) % 3];
        const bool do_stage = (kk < 14);

        // ---- phase A: read af0-3 + bf0-3, stage half, MFMA ni 0-3 ----
        v4i af[4], bf[4];
#pragma unroll
        for (int mi = 0; mi < 4; ++mi) af[mi] = *(const v4i*)(Ab + aOff + mi * 1024);
#pragma unroll
        for (int ni = 0; ni < 4; ++ni) bf[ni] = *(const v4i*)(Bb + bOff + ni * 1024);
        if (do_stage) STAGE_HALF(Ast, Bst, kk + 2, 0);
        __builtin_amdgcn_sched_barrier(0);
        __builtin_amdgcn_s_barrier();
        asm volatile("s_waitcnt lgkmcnt(0)" ::: "memory");
        __builtin_amdgcn_sched_barrier(0);
        __builtin_amdgcn_s_setprio(1);
#pragma unroll
        for (int mi = 0; mi < 4; ++mi)
#pragma unroll
            for (int ni = 0; ni < 4; ++ni)
                acc[mi][ni] = __builtin_amdgcn_mfma_i32_16x16x64_i8(
                    af[mi], bf[ni], acc[mi][ni], 0, 0, 0);
        __builtin_amdgcn_s_setprio(0);
        __builtin_amdgcn_sched_barrier(0);
        __builtin_amdgcn_s_barrier();

        // ---- phase B: read bf4-7, stage other half, MFMA ni 4-7 ----
#pragma unroll
        for (int ni = 0; ni < 4; ++ni)
            bf[ni] = *(const v4i*)(Bb + bOff + 4096 + ni * 1024);
        if (do_stage) STAGE_HALF(Ast, Bst, kk + 2, 1);
        __builtin_amdgcn_sched_barrier(0);
        __builtin_amdgcn_s_barrier();
        asm volatile("s_waitcnt lgkmcnt(0)" ::: "memory");
        __builtin_amdgcn_sched_barrier(0);
        __builtin_amdgcn_s_setprio(1);
#pragma unroll
        for (int mi = 0; mi < 4; ++mi)
#pragma unroll
            for (int ni = 0; ni < 4; ++ni)
                acc[mi][4 + ni] = __builtin_amdgcn_mfma_i32_16x16x64_i8(
                    af[mi], bf[ni], acc[mi][4 + ni], 0, 0, 0);
        __builtin_amdgcn_s_setprio(0);
        __builtin_amdgcn_sched_barrier(0);

        // ---- tile end: counted wait for next buffer, then block-wide sync.
        if (kk < 14) {
            asm volatile("s_waitcnt vmcnt(6)" ::: "memory");  // tile kk+1 resident
            __builtin_amdgcn_s_barrier();
        } else if (kk == 14) {
            asm volatile("s_waitcnt vmcnt(0)" ::: "memory");  // tile 15 resident
            __builtin_amdgcn_s_barrier();
        }
    }

    // Epilogue: atomic accumulation into denom[8192].
    // C/D: col = ni*16 + cm (tile-local), row = wv*64 + mi*16 + q*4 + reg.
    const float esc = 2.0f / 16129.0f;  // (1/T) / 127^2
    float colsum[8];
#pragma unroll
    for (int ni = 0; ni < 8; ++ni) colsum[ni] = 0.f;

#pragma unroll
    for (int mi = 0; mi < 4; ++mi) {
#pragma unroll
        for (int reg = 0; reg < 4; ++reg) {
            const int grow = rb * 256 + wv * 64 + mi * 16 + (q << 2) + reg;
            float rs = 0.f;
#pragma unroll
            for (int ni = 0; ni < 8; ++ni) {
                const int gcol = cb * 128 + ni * 16 + cm;
                const float e =
                    (grow == gcol) ? 0.f : __expf((float)acc[mi][ni][reg] * esc);
                rs += e;
                colsum[ni] += e;
            }
            rs += __shfl_xor(rs, 1);
            rs += __shfl_xor(rs, 2);
            rs += __shfl_xor(rs, 4);
            rs += __shfl_xor(rs, 8);
            if (cm == 0) atomicAdd(denom + grow, rs);  // rowsum
        }
    }

    // colsum: include only pairs whose primary tile is NOT in the set.
    const bool pred = (2 * rb + (wv >> 1)) < 2 * (cb >> 1);
#pragma unroll
    for (int ni = 0; ni < 8; ++ni) {
        colsum[ni] += __shfl_xor(colsum[ni], 16);  // fold q (rows)
        colsum[ni] += __shfl_xor(colsum[ni], 32);
    }
    if (pred && q == 0) {
#pragma unroll
        for (int ni = 0; ni < 8; ++ni)
            atomicAdd(denom + cb * 128 + ni * 16 + cm, colsum[ni]);
    }
}

// Kernel 3: finish — one thread per row: loss_r = log(denom_r) - 2*pos,
// block-reduce, single atomicAdd per block into out (out zeroed by kernel 1).
__global__ void finish_kernel(const float* __restrict__ denom,
                              const float* __restrict__ pos,
                              float* __restrict__ out) {
    const int r = blockIdx.x * 256 + threadIdx.x;  // 32 x 256 = 8192
    float v = __logf(denom[r]) - pos[r & (B_ROWS - 1)] * 2.0f;
    v = wave_reduce_sum(v);
    __shared__ float red[4];
    const int lane = threadIdx.x & 63, wv = threadIdx.x >> 6;
    if (lane == 0) red[wv] = v;
    __syncthreads();
    if (threadIdx.x == 0)
        atomicAdd(out, (red[0] + red[1] + red[2] + red[3]) * (1.0f / NN));
}

extern "C" void kernel_launch(void* const* d_in, const int* in_sizes, int n_in,
                              void* d_out, int out_size, void* d_ws, size_t ws_size,
                              hipStream_t stream) {
    const float* p1 = (const float*)d_in[0];
    const float* p2 = (const float*)d_in[1];
    char* ws = (char*)d_ws;
    signed char* rep = (signed char*)ws;                            // 8 MiB (i8)
    float* pos = (float*)(ws + (size_t)8 * 1024 * 1024);            // 16 KiB
    float* denom = (float*)(ws + (size_t)8 * 1024 * 1024 + 16384);  // 32 KiB
    float* out = (float*)d_out;

    norm_pos_kernel<<<1024, 256, 0, stream>>>(p1, p2, rep, pos, denom, out);
    gemm_kernel<<<1056, 256, 0, stream>>>(rep, denom);
    finish_kernel<<<32, 256, 0, stream>>>(denom, pos, out);
}